// Round 6
// baseline (1063.259 us; speedup 1.0000x reference)
//
#include <hip/hip_runtime.h>

#define BS   8192
#define DIM  1024
#define TINV 10.0f    // 1 / TEMPERATURE
#define MARGIN 1.0f   // max(0.01, 1.0 - 0.1*0.0)

#define BM  128
#define BN  128
#define BKB 128       // fp8 K-elements (= bytes) per staging iteration

// fp8 values are the normalized elements scaled by 16 -> dot = 256 * cos
#define QSCALE   16.0f
#define INV_QSQ  (1.0f / 256.0f)

typedef __attribute__((ext_vector_type(4))) float f32x4;
typedef __attribute__((ext_vector_type(4))) int   int4v;
typedef __attribute__((ext_vector_type(8))) int   int8v;

// ---------------- Kernel 1: L2-normalize rows, emit fp8(e4m3,x16) + posdist -
__global__ __launch_bounds__(256) void normalize_kernel(
    const float* __restrict__ feat,
    unsigned char* __restrict__ Afp8,
    unsigned char* __restrict__ Nfp8,
    float* __restrict__ posdist)
{
    const int row  = blockIdx.x;
    const int tid  = threadIdx.x;
    const int lane = tid & 63;
    const int w    = tid >> 6;
    __shared__ float red[4][4];

    const float4* fo = (const float4*)(feat + (size_t)row * DIM);
    const float4* fp = (const float4*)(feat + (size_t)(BS + row) * DIM);
    const float4* fn = (const float4*)(feat + (size_t)(2 * BS + row) * DIM);
    float4 o = fo[tid], p = fp[tid], n = fn[tid];

    float so = o.x*o.x + o.y*o.y + o.z*o.z + o.w*o.w;
    float sp = p.x*p.x + p.y*p.y + p.z*p.z + p.w*p.w;
    float sn = n.x*n.x + n.y*n.y + n.z*n.z + n.w*n.w;
    #pragma unroll
    for (int off = 1; off < 64; off <<= 1) {
        so += __shfl_xor(so, off);
        sp += __shfl_xor(sp, off);
        sn += __shfl_xor(sn, off);
    }
    if (lane == 0) { red[w][0] = so; red[w][1] = sp; red[w][2] = sn; }
    __syncthreads();
    so = red[0][0] + red[1][0] + red[2][0] + red[3][0];
    sp = red[0][1] + red[1][1] + red[2][1] + red[3][1];
    sn = red[0][2] + red[1][2] + red[2][2] + red[3][2];

    const float io  = 1.0f / fmaxf(sqrtf(so), 1e-12f);
    const float ip  = 1.0f / fmaxf(sqrtf(sp), 1e-12f);
    const float in_ = 1.0f / fmaxf(sqrtf(sn), 1e-12f);

    float ax = o.x*io, ay = o.y*io, az = o.z*io, aw = o.w*io;
    float px = p.x*ip, py = p.y*ip, pz = p.z*ip, pw = p.w*ip;
    float nx = n.x*in_, ny = n.y*in_, nz = n.z*in_, nw = n.w*in_;

    // e4m3 quantization with x16 pre-scale (avoids subnormals; max elem 16 << 448)
    int pa = __builtin_amdgcn_cvt_pk_fp8_f32(ax * QSCALE, ay * QSCALE, 0, false);
    pa     = __builtin_amdgcn_cvt_pk_fp8_f32(az * QSCALE, aw * QSCALE, pa, true);
    int pn = __builtin_amdgcn_cvt_pk_fp8_f32(nx * QSCALE, ny * QSCALE, 0, false);
    pn     = __builtin_amdgcn_cvt_pk_fp8_f32(nz * QSCALE, nw * QSCALE, pn, true);
    ((int*)(Afp8 + (size_t)row * DIM))[tid] = pa;
    ((int*)(Nfp8 + (size_t)row * DIM))[tid] = pn;

    float dx = ax - px, dy = ay - py, dz = az - pz, dw = aw - pw;
    float d = dx*dx + dy*dy + dz*dz + dw*dw;
    #pragma unroll
    for (int off = 1; off < 64; off <<= 1) d += __shfl_xor(d, off);
    if (lane == 0) red[w][3] = d;   // col 3: disjoint from cols 0..2 read above
    __syncthreads();
    if (tid == 0)
        posdist[row] = (red[0][3] + red[1][3] + red[2][3] + red[3][3]) * TINV;
}

// Load one 32B A/B fragment from swizzled LDS: lo chunk at `off`, hi at off^16
// (q2 even => (q2+1)^x == (q2^x)^1 => +-16 bytes). Union avoids v_mov repack.
__device__ __forceinline__ int8v ld_frag(const unsigned char* __restrict__ p,
                                         int off) {
    union { int8v v; struct { int4v lo, hi; } s; } u;
    u.s.lo = *(const int4v*)(p + off);
    u.s.hi = *(const int4v*)(p + (off ^ 16));
    return u.v;
}

// ---------------- Kernel 2: MX-fp8 MFMA max-GEMM (C = A . N^T, row-max) -----
// __launch_bounds__(256,4): force VGPR<=128 (R5: 236 VGPR -> 11% occupancy,
// MfmaUtil 16.6%; essentials fit in ~124: acc 64 + bfr 32 + af 8 + addr ~20).
// Inner loop streams af one fragment at a time against 4 resident bfr.
// LDS XOR-chunk swizzle as R4/R5: LDS(row r, 16B chunk c) = global chunk c^(r&7).
__global__ __launch_bounds__(256, 4) void maxgemm_kernel(
    const unsigned char* __restrict__ Afp8,
    const unsigned char* __restrict__ Nfp8,
    float* __restrict__ partial)   // [BS][128] row-major
{
    __shared__ unsigned char As[BM * BKB];
    __shared__ unsigned char Bs[BN * BKB];

    const int tid  = threadIdx.x;
    const int lane = tid & 63;
    const int w    = tid >> 6;
    const int wm   = w >> 1, wn = w & 1;
    const int rowBase = blockIdx.y * BM;
    const int colBase = blockIdx.x * BN;

    const int lrow = lane >> 3;                      // 0..7: row in 8-row slab
    const int gcol = ((lane & 7) ^ lrow) * 16;       // swizzled 16B chunk (bytes)

    // Per-lane global staging bases (slab c adds c*8*DIM, iter adds k0)
    const unsigned char* AgL = Afp8 + (size_t)(rowBase + w * 32 + lrow) * DIM + gcol;
    const unsigned char* BgL = Nfp8 + (size_t)(colBase + w * 32 + lrow) * DIM + gcol;

    // Per-lane LDS read offsets (i-invariant XOR term: (row+i*16)&7 == row&7)
    const int q2   = (lane >> 4) * 2;                // first 16B chunk of quad
    const int arow = wm * 64 + (lane & 15);
    const int brow = wn * 64 + (lane & 15);
    const int aoff = arow * BKB + ((q2 ^ (arow & 7)) << 4);
    const int boff = brow * BKB + ((q2 ^ (brow & 7)) << 4);

    f32x4 acc[4][4];
    #pragma unroll
    for (int i = 0; i < 4; i++)
        #pragma unroll
        for (int j = 0; j < 4; j++)
            acc[i][j] = (f32x4){0.f, 0.f, 0.f, 0.f};

    for (int k0 = 0; k0 < DIM; k0 += BKB) {
        __syncthreads();  // prior iter's LDS reads done
        #pragma unroll
        for (int c = 0; c < 4; c++) {
            const int sl = (w * 4 + c) * 8;   // slab start row; wave-uniform
            __builtin_amdgcn_global_load_lds(
                (const __attribute__((address_space(1))) void*)
                    (AgL + (size_t)c * 8 * DIM + k0),
                (__attribute__((address_space(3))) void*)(As + sl * BKB),
                16, 0, 0);
            __builtin_amdgcn_global_load_lds(
                (const __attribute__((address_space(1))) void*)
                    (BgL + (size_t)c * 8 * DIM + k0),
                (__attribute__((address_space(3))) void*)(Bs + sl * BKB),
                16, 0, 0);
        }
        __syncthreads();  // vmcnt drained by barrier semantics

        int8v bfr[4];
        #pragma unroll
        for (int j = 0; j < 4; j++)
            bfr[j] = ld_frag(Bs, boff + j * 16 * BKB);

        #pragma unroll
        for (int i = 0; i < 4; i++) {
            const int8v a = ld_frag(As, aoff + i * 16 * BKB);
            #pragma unroll
            for (int j = 0; j < 4; j++)
                acc[i][j] = __builtin_amdgcn_mfma_scale_f32_16x16x128_f8f6f4(
                    a, bfr[j], acc[i][j],
                    0, 0,               // cbsz=FP8(e4m3), blgp=FP8(e4m3)
                    0, 0x7F7F7F7F,      // opselA, scaleA = 1.0
                    0, 0x7F7F7F7F);     // opselB, scaleB = 1.0
        }
    }

    // Epilogue: per-row max over this wave's 64 columns, write one stripe value.
    // C/D layout (verified m89/m91): col = lane&15, row = (lane>>4)*4 + reg.
    const int stripe = blockIdx.x * 2 + wn;
    #pragma unroll
    for (int i = 0; i < 4; i++) {
        #pragma unroll
        for (int r = 0; r < 4; r++) {
            float v = fmaxf(fmaxf(acc[i][0][r], acc[i][1][r]),
                            fmaxf(acc[i][2][r], acc[i][3][r]));
            v = fmaxf(v, __shfl_xor(v, 1));
            v = fmaxf(v, __shfl_xor(v, 2));
            v = fmaxf(v, __shfl_xor(v, 4));
            v = fmaxf(v, __shfl_xor(v, 8));
            if ((lane & 15) == 0) {
                const int row = rowBase + wm * 64 + i * 16 + (lane >> 4) * 4 + r;
                partial[(size_t)row * 128 + stripe] = v;   // = 256 * cos
            }
        }
    }
}

// ---------------- Kernel 3: stripe-max -> loss terms -> per-block partials --
__global__ __launch_bounds__(256) void reduce_kernel(
    const float* __restrict__ partial,
    const float* __restrict__ posdist,
    float* __restrict__ blockpart)   // [64][3]
{
    const int tid  = threadIdx.x;
    const int lane = tid & 63;
    const int w    = tid >> 6;
    __shared__ float red[4][3];

    float sloss = 0.f, spos = 0.f, shard = 0.f;

    #pragma unroll 4
    for (int i = 0; i < 32; i++) {
        const int row = blockIdx.x * 128 + w * 32 + i;
        float v = fmaxf(partial[(size_t)row * 128 + lane],
                        partial[(size_t)row * 128 + 64 + lane]);
        #pragma unroll
        for (int off = 1; off < 64; off <<= 1) v = fmaxf(v, __shfl_xor(v, off));
        if (lane == 0) {
            // v = 256*cos  ->  hard = (2 - 2*cos)/T = (2 - v/128)*TINV
            const float hard = (2.0f - 2.0f * v * INV_QSQ) * TINV;
            const float pos  = posdist[row];
            sloss += fmaxf(MARGIN + pos - hard, 0.0f);
            spos  += pos;
            shard += hard;
        }
    }
    if (lane == 0) { red[w][0] = sloss; red[w][1] = spos; red[w][2] = shard; }
    __syncthreads();
    if (tid == 0) {
        #pragma unroll
        for (int k = 0; k < 3; k++)
            blockpart[blockIdx.x * 3 + k] =
                red[0][k] + red[1][k] + red[2][k] + red[3][k];
    }
}

// ---------------- Kernel 4: finalize means (one wave, no atomics) -----------
__global__ __launch_bounds__(64) void finalize_kernel(
    const float* __restrict__ blockpart,
    float* __restrict__ out)
{
    const int lane = threadIdx.x;
    float a = blockpart[lane * 3 + 0];
    float b = blockpart[lane * 3 + 1];
    float c = blockpart[lane * 3 + 2];
    #pragma unroll
    for (int off = 1; off < 64; off <<= 1) {
        a += __shfl_xor(a, off);
        b += __shfl_xor(b, off);
        c += __shfl_xor(c, off);
    }
    if (lane == 0) {
        const float inv = 1.0f / (float)BS;
        out[0] = a * inv;
        out[1] = b * inv;
        out[2] = c * inv;
    }
}

extern "C" void kernel_launch(void* const* d_in, const int* in_sizes, int n_in,
                              void* d_out, int out_size, void* d_ws, size_t ws_size,
                              hipStream_t stream) {
    const float* feat = (const float*)d_in[0];
    char* ws = (char*)d_ws;

    // ws layout: Afp8 8MiB | Nfp8 8MiB | partial 4MiB | posdist 32KiB | blockpart
    unsigned char* Afp8      = (unsigned char*)ws;
    unsigned char* Nfp8      = (unsigned char*)(ws + ((size_t)8 << 20));
    float*         partial   = (float*)(ws + ((size_t)16 << 20));
    float*         posdist   = (float*)(ws + ((size_t)20 << 20));
    float*         blockpart = (float*)(ws + ((size_t)20 << 20) + 32768);

    normalize_kernel<<<BS, 256, 0, stream>>>(feat, Afp8, Nfp8, posdist);

    maxgemm_kernel<<<dim3(BS / BN, BS / BM), 256, 0, stream>>>(Afp8, Nfp8, partial);

    reduce_kernel<<<64, 256, 0, stream>>>(partial, posdist, blockpart);
    finalize_kernel<<<1, 64, 0, stream>>>(blockpart, (float*)d_out);
}

// Round 7
// 858.869 us; speedup vs baseline: 1.2380x; 1.2380x over previous
//
#include <hip/hip_runtime.h>

#define BS   8192
#define DIM  1024
#define TINV 10.0f    // 1 / TEMPERATURE
#define MARGIN 1.0f   // max(0.01, 1.0 - 0.1*0.0)

#define BM  128
#define BN  128
#define BKB 128       // fp8 K-elements (= bytes) per staging iteration

// fp8 values are the normalized elements scaled by 16 -> dot = 256 * cos
#define QSCALE   16.0f
#define INV_QSQ  (1.0f / 256.0f)

typedef __attribute__((ext_vector_type(4))) float f32x4;
typedef __attribute__((ext_vector_type(4))) int   int4v;
typedef __attribute__((ext_vector_type(8))) int   int8v;

// ---------------- Kernel 1: L2-normalize rows, emit fp8(e4m3,x16) + posdist -
__global__ __launch_bounds__(256) void normalize_kernel(
    const float* __restrict__ feat,
    unsigned char* __restrict__ Afp8,
    unsigned char* __restrict__ Nfp8,
    float* __restrict__ posdist)
{
    const int row  = blockIdx.x;
    const int tid  = threadIdx.x;
    const int lane = tid & 63;
    const int w    = tid >> 6;
    __shared__ float red[4][4];

    const float4* fo = (const float4*)(feat + (size_t)row * DIM);
    const float4* fp = (const float4*)(feat + (size_t)(BS + row) * DIM);
    const float4* fn = (const float4*)(feat + (size_t)(2 * BS + row) * DIM);
    float4 o = fo[tid], p = fp[tid], n = fn[tid];

    float so = o.x*o.x + o.y*o.y + o.z*o.z + o.w*o.w;
    float sp = p.x*p.x + p.y*p.y + p.z*p.z + p.w*p.w;
    float sn = n.x*n.x + n.y*n.y + n.z*n.z + n.w*n.w;
    #pragma unroll
    for (int off = 1; off < 64; off <<= 1) {
        so += __shfl_xor(so, off);
        sp += __shfl_xor(sp, off);
        sn += __shfl_xor(sn, off);
    }
    if (lane == 0) { red[w][0] = so; red[w][1] = sp; red[w][2] = sn; }
    __syncthreads();
    so = red[0][0] + red[1][0] + red[2][0] + red[3][0];
    sp = red[0][1] + red[1][1] + red[2][1] + red[3][1];
    sn = red[0][2] + red[1][2] + red[2][2] + red[3][2];

    const float io  = 1.0f / fmaxf(sqrtf(so), 1e-12f);
    const float ip  = 1.0f / fmaxf(sqrtf(sp), 1e-12f);
    const float in_ = 1.0f / fmaxf(sqrtf(sn), 1e-12f);

    float ax = o.x*io, ay = o.y*io, az = o.z*io, aw = o.w*io;
    float px = p.x*ip, py = p.y*ip, pz = p.z*ip, pw = p.w*ip;
    float nx = n.x*in_, ny = n.y*in_, nz = n.z*in_, nw = n.w*in_;

    // e4m3 quantization with x16 pre-scale (avoids subnormals; max elem 16 << 448)
    int pa = __builtin_amdgcn_cvt_pk_fp8_f32(ax * QSCALE, ay * QSCALE, 0, false);
    pa     = __builtin_amdgcn_cvt_pk_fp8_f32(az * QSCALE, aw * QSCALE, pa, true);
    int pn = __builtin_amdgcn_cvt_pk_fp8_f32(nx * QSCALE, ny * QSCALE, 0, false);
    pn     = __builtin_amdgcn_cvt_pk_fp8_f32(nz * QSCALE, nw * QSCALE, pn, true);
    ((int*)(Afp8 + (size_t)row * DIM))[tid] = pa;
    ((int*)(Nfp8 + (size_t)row * DIM))[tid] = pn;

    float dx = ax - px, dy = ay - py, dz = az - pz, dw = aw - pw;
    float d = dx*dx + dy*dy + dz*dz + dw*dw;
    #pragma unroll
    for (int off = 1; off < 64; off <<= 1) d += __shfl_xor(d, off);
    if (lane == 0) red[w][3] = d;   // col 3: disjoint from cols 0..2 read above
    __syncthreads();
    if (tid == 0)
        posdist[row] = (red[0][3] + red[1][3] + red[2][3] + red[3][3]) * TINV;
}

// ---------------- Kernel 2: MX-fp8 MFMA max-GEMM (C = A . N^T, row-max) -----
// Structure = R5 (known-good 162 us). ONLY change: __launch_bounds__(256,3)
// -> VGPR cap ~168. R5 free allocation was 236 VGPR -> 2 waves/SIMD, 11%
// occupancy, MfmaUtil 16.6%. R6's (256,4) cap=128 < essentials (~140) ->
// 1.5 GB scratch spill, 892 us. Essentials fit in ~130, so 168 leaves
// pipelining headroom without spill. Tripwire: WRITE_SIZE must stay ~16 MB.
// LDS XOR-chunk swizzle: LDS(row r, 16B chunk c) = global chunk c^(r&7).
__global__ __launch_bounds__(256, 3) void maxgemm_kernel(
    const unsigned char* __restrict__ Afp8,
    const unsigned char* __restrict__ Nfp8,
    float* __restrict__ partial)   // [BS][128] row-major
{
    __shared__ unsigned char As[BM * BKB];
    __shared__ unsigned char Bs[BN * BKB];

    const int tid  = threadIdx.x;
    const int lane = tid & 63;
    const int w    = tid >> 6;
    const int wm   = w >> 1, wn = w & 1;
    const int rowBase = blockIdx.y * BM;
    const int colBase = blockIdx.x * BN;

    const int lrow = lane >> 3;                      // 0..7: row in 8-row slab
    const int gcol = ((lane & 7) ^ lrow) * 16;       // swizzled 16B chunk (bytes)

    const unsigned char* Ag = Afp8 + (size_t)rowBase * DIM;
    const unsigned char* Bg = Nfp8 + (size_t)colBase * DIM;

    f32x4 acc[4][4];
    #pragma unroll
    for (int i = 0; i < 4; i++)
        #pragma unroll
        for (int j = 0; j < 4; j++)
            acc[i][j] = (f32x4){0.f, 0.f, 0.f, 0.f};

    for (int k0 = 0; k0 < DIM; k0 += BKB) {
        __syncthreads();  // prior iter's LDS reads done
        #pragma unroll
        for (int c = 0; c < 4; c++) {
            const int r0 = (w * 4 + c) * 8;   // 8-row slab; wave-uniform
            __builtin_amdgcn_global_load_lds(
                (const __attribute__((address_space(1))) void*)
                    (Ag + (size_t)(r0 + lrow) * DIM + k0 + gcol),
                (__attribute__((address_space(3))) void*)(As + r0 * BKB),
                16, 0, 0);
            __builtin_amdgcn_global_load_lds(
                (const __attribute__((address_space(1))) void*)
                    (Bg + (size_t)(r0 + lrow) * DIM + k0 + gcol),
                (__attribute__((address_space(3))) void*)(Bs + r0 * BKB),
                16, 0, 0);
        }
        __syncthreads();  // vmcnt drained by barrier semantics

        const int q2 = (lane >> 4) * 2;   // first of this quad's two 16B chunks
        int8v af[4], bfr[4];
        #pragma unroll
        for (int i = 0; i < 4; i++) {
            const int ar = wm * 64 + i * 16 + (lane & 15);
            const unsigned char* pa = As + ar * BKB;
            int4v alo = *(const int4v*)(pa + ((q2 ^ (ar & 7)) << 4));
            int4v ahi = *(const int4v*)(pa + (((q2 + 1) ^ (ar & 7)) << 4));
            af[i] = (int8v){alo[0], alo[1], alo[2], alo[3],
                            ahi[0], ahi[1], ahi[2], ahi[3]};
            const int br = wn * 64 + i * 16 + (lane & 15);
            const unsigned char* pb = Bs + br * BKB;
            int4v blo = *(const int4v*)(pb + ((q2 ^ (br & 7)) << 4));
            int4v bhi = *(const int4v*)(pb + (((q2 + 1) ^ (br & 7)) << 4));
            bfr[i] = (int8v){blo[0], blo[1], blo[2], blo[3],
                             bhi[0], bhi[1], bhi[2], bhi[3]};
        }
        #pragma unroll
        for (int i = 0; i < 4; i++)
            #pragma unroll
            for (int j = 0; j < 4; j++)
                acc[i][j] = __builtin_amdgcn_mfma_scale_f32_16x16x128_f8f6f4(
                    af[i], bfr[j], acc[i][j],
                    0, 0,               // cbsz=FP8(e4m3), blgp=FP8(e4m3)
                    0, 0x7F7F7F7F,      // opselA, scaleA = 1.0
                    0, 0x7F7F7F7F);     // opselB, scaleB = 1.0
    }

    // Epilogue: per-row max over this wave's 64 columns, write one stripe value.
    // C/D layout (verified m89/m91): col = lane&15, row = (lane>>4)*4 + reg.
    const int stripe = blockIdx.x * 2 + wn;
    #pragma unroll
    for (int i = 0; i < 4; i++) {
        #pragma unroll
        for (int r = 0; r < 4; r++) {
            float v = fmaxf(fmaxf(acc[i][0][r], acc[i][1][r]),
                            fmaxf(acc[i][2][r], acc[i][3][r]));
            v = fmaxf(v, __shfl_xor(v, 1));
            v = fmaxf(v, __shfl_xor(v, 2));
            v = fmaxf(v, __shfl_xor(v, 4));
            v = fmaxf(v, __shfl_xor(v, 8));
            if ((lane & 15) == 0) {
                const int row = rowBase + wm * 64 + i * 16 + (lane >> 4) * 4 + r;
                partial[(size_t)row * 128 + stripe] = v;   // = 256 * cos
            }
        }
    }
}

// ---------------- Kernel 3: stripe-max -> loss terms -> per-block partials --
__global__ __launch_bounds__(256) void reduce_kernel(
    const float* __restrict__ partial,
    const float* __restrict__ posdist,
    float* __restrict__ blockpart)   // [64][3]
{
    const int tid  = threadIdx.x;
    const int lane = tid & 63;
    const int w    = tid >> 6;
    __shared__ float red[4][3];

    float sloss = 0.f, spos = 0.f, shard = 0.f;

    #pragma unroll 4
    for (int i = 0; i < 32; i++) {
        const int row = blockIdx.x * 128 + w * 32 + i;
        float v = fmaxf(partial[(size_t)row * 128 + lane],
                        partial[(size_t)row * 128 + 64 + lane]);
        #pragma unroll
        for (int off = 1; off < 64; off <<= 1) v = fmaxf(v, __shfl_xor(v, off));
        if (lane == 0) {
            // v = 256*cos  ->  hard = (2 - 2*cos)/T = (2 - v/128)*TINV
            const float hard = (2.0f - 2.0f * v * INV_QSQ) * TINV;
            const float pos  = posdist[row];
            sloss += fmaxf(MARGIN + pos - hard, 0.0f);
            spos  += pos;
            shard += hard;
        }
    }
    if (lane == 0) { red[w][0] = sloss; red[w][1] = spos; red[w][2] = shard; }
    __syncthreads();
    if (tid == 0) {
        #pragma unroll
        for (int k = 0; k < 3; k++)
            blockpart[blockIdx.x * 3 + k] =
                red[0][k] + red[1][k] + red[2][k] + red[3][k];
    }
}

// ---------------- Kernel 4: finalize means (one wave, no atomics) -----------
__global__ __launch_bounds__(64) void finalize_kernel(
    const float* __restrict__ blockpart,
    float* __restrict__ out)
{
    const int lane = threadIdx.x;
    float a = blockpart[lane * 3 + 0];
    float b = blockpart[lane * 3 + 1];
    float c = blockpart[lane * 3 + 2];
    #pragma unroll
    for (int off = 1; off < 64; off <<= 1) {
        a += __shfl_xor(a, off);
        b += __shfl_xor(b, off);
        c += __shfl_xor(c, off);
    }
    if (lane == 0) {
        const float inv = 1.0f / (float)BS;
        out[0] = a * inv;
        out[1] = b * inv;
        out[2] = c * inv;
    }
}

extern "C" void kernel_launch(void* const* d_in, const int* in_sizes, int n_in,
                              void* d_out, int out_size, void* d_ws, size_t ws_size,
                              hipStream_t stream) {
    const float* feat = (const float*)d_in[0];
    char* ws = (char*)d_ws;

    // ws layout: Afp8 8MiB | Nfp8 8MiB | partial 4MiB | posdist 32KiB | blockpart
    unsigned char* Afp8      = (unsigned char*)ws;
    unsigned char* Nfp8      = (unsigned char*)(ws + ((size_t)8 << 20));
    float*         partial   = (float*)(ws + ((size_t)16 << 20));
    float*         posdist   = (float*)(ws + ((size_t)20 << 20));
    float*         blockpart = (float*)(ws + ((size_t)20 << 20) + 32768);

    normalize_kernel<<<BS, 256, 0, stream>>>(feat, Afp8, Nfp8, posdist);

    maxgemm_kernel<<<dim3(BS / BN, BS / BM), 256, 0, stream>>>(Afp8, Nfp8, partial);

    reduce_kernel<<<64, 256, 0, stream>>>(partial, posdist, blockpart);
    finalize_kernel<<<1, 64, 0, stream>>>(blockpart, (float*)d_out);
}

// Round 8
// 389.107 us; speedup vs baseline: 2.7326x; 2.2073x over previous
//
#include <hip/hip_runtime.h>

#define BS   8192
#define DIM  1024
#define TINV 10.0f    // 1 / TEMPERATURE
#define MARGIN 1.0f   // max(0.01, 1.0 - 0.1*0.0)

#define BM  128
#define BN  128
#define BKB 64        // fp8 K-bytes per staging iteration (32x32x64 MFMA)

// fp8 values are the normalized elements scaled by 16 -> dot = 256 * cos
#define QSCALE   16.0f
#define INV_QSQ  (1.0f / 256.0f)

typedef __attribute__((ext_vector_type(4)))  float f32x4;
typedef __attribute__((ext_vector_type(16))) float f32x16;
typedef __attribute__((ext_vector_type(4)))  int   int4v;
typedef __attribute__((ext_vector_type(8)))  int   int8v;

// ---------------- Kernel 1: L2-normalize rows, emit fp8(e4m3,x16) + posdist -
__global__ __launch_bounds__(256) void normalize_kernel(
    const float* __restrict__ feat,
    unsigned char* __restrict__ Afp8,
    unsigned char* __restrict__ Nfp8,
    float* __restrict__ posdist)
{
    const int row  = blockIdx.x;
    const int tid  = threadIdx.x;
    const int lane = tid & 63;
    const int w    = tid >> 6;
    __shared__ float red[4][4];

    const float4* fo = (const float4*)(feat + (size_t)row * DIM);
    const float4* fp = (const float4*)(feat + (size_t)(BS + row) * DIM);
    const float4* fn = (const float4*)(feat + (size_t)(2 * BS + row) * DIM);
    float4 o = fo[tid], p = fp[tid], n = fn[tid];

    float so = o.x*o.x + o.y*o.y + o.z*o.z + o.w*o.w;
    float sp = p.x*p.x + p.y*p.y + p.z*p.z + p.w*p.w;
    float sn = n.x*n.x + n.y*n.y + n.z*n.z + n.w*n.w;
    #pragma unroll
    for (int off = 1; off < 64; off <<= 1) {
        so += __shfl_xor(so, off);
        sp += __shfl_xor(sp, off);
        sn += __shfl_xor(sn, off);
    }
    if (lane == 0) { red[w][0] = so; red[w][1] = sp; red[w][2] = sn; }
    __syncthreads();
    so = red[0][0] + red[1][0] + red[2][0] + red[3][0];
    sp = red[0][1] + red[1][1] + red[2][1] + red[3][1];
    sn = red[0][2] + red[1][2] + red[2][2] + red[3][2];

    const float io  = 1.0f / fmaxf(sqrtf(so), 1e-12f);
    const float ip  = 1.0f / fmaxf(sqrtf(sp), 1e-12f);
    const float in_ = 1.0f / fmaxf(sqrtf(sn), 1e-12f);

    float ax = o.x*io, ay = o.y*io, az = o.z*io, aw = o.w*io;
    float px = p.x*ip, py = p.y*ip, pz = p.z*ip, pw = p.w*ip;
    float nx = n.x*in_, ny = n.y*in_, nz = n.z*in_, nw = n.w*in_;

    // e4m3 quantization with x16 pre-scale (avoids subnormals; max elem 16 << 448)
    int pa = __builtin_amdgcn_cvt_pk_fp8_f32(ax * QSCALE, ay * QSCALE, 0, false);
    pa     = __builtin_amdgcn_cvt_pk_fp8_f32(az * QSCALE, aw * QSCALE, pa, true);
    int pn = __builtin_amdgcn_cvt_pk_fp8_f32(nx * QSCALE, ny * QSCALE, 0, false);
    pn     = __builtin_amdgcn_cvt_pk_fp8_f32(nz * QSCALE, nw * QSCALE, pn, true);
    ((int*)(Afp8 + (size_t)row * DIM))[tid] = pa;
    ((int*)(Nfp8 + (size_t)row * DIM))[tid] = pn;

    float dx = ax - px, dy = ay - py, dz = az - pz, dw = aw - pw;
    float d = dx*dx + dy*dy + dz*dz + dw*dw;
    #pragma unroll
    for (int off = 1; off < 64; off <<= 1) d += __shfl_xor(d, off);
    if (lane == 0) red[w][3] = d;   // col 3: disjoint from cols 0..2 read above
    __syncthreads();
    if (tid == 0)
        posdist[row] = (red[0][3] + red[1][3] + red[2][3] + red[3][3]) * TINV;
}

// ---------------- Kernel 2: MX-fp8 32x32x64 MFMA max-GEMM -------------------
// Why 32x32x64 (vs R5's 16x16x128): same 4 KB LDS-read per MFMA but 2x the
// FLOP -> LDS bytes/FLOP halves (R5 was LDS-BW-bound: 8.6 GB @69 TB/s = 125us
// floor; now 4.3 GB = 62us). Fragment regs halve (af[2]+bf[2]=32) so free
// allocation should fit 3 waves/SIMD WITHOUT __launch_bounds__ (R6/R7 lesson:
// any cap below the allocator's need -> GB-scale scratch spill).
// LDS swizzle for 64B rows: global 16B-chunk k of row r lives at LDS chunk
// (k + (r>>1)) & 3. Staging is per-lane-constant (legal for global_load_lds);
// read bank-groups (4*(m&1)+c)%8 cover all 8 uniformly for both k-halves.
__global__ __launch_bounds__(256) void maxgemm_kernel(
    const unsigned char* __restrict__ Afp8,
    const unsigned char* __restrict__ Nfp8,
    float* __restrict__ partial)   // [BS][128] row-major
{
    __shared__ unsigned char As[BM * BKB];
    __shared__ unsigned char Bs[BN * BKB];

    const int tid  = threadIdx.x;
    const int lane = tid & 63;
    const int w    = tid >> 6;
    const int wm   = w >> 1, wn = w & 1;
    const int rowBase = blockIdx.y * BM;
    const int colBase = blockIdx.x * BN;

    // Staging map: lane L -> slab row L>>2, LDS chunk L&3,
    // global chunk ((L&3) - ((L>>3)&3)) & 3   [= sigma(r,c), r0 mult of 16]
    const int srow   = lane >> 2;
    const int gchunk = ((lane & 3) - ((lane >> 3) & 3)) & 3;
    // Wave w stages A rows [w*32, w*32+32) and B rows [w*32, w*32+32): 2 instrs each.
    const unsigned char* AgL =
        Afp8 + (size_t)(rowBase + w * 32 + srow) * DIM + gchunk * 16;
    const unsigned char* BgL =
        Nfp8 + (size_t)(colBase + w * 32 + srow) * DIM + gchunk * 16;

    // Read map: a-frag row m = base + (lane&31), k-half h = lane>>5.
    // LDS chunk of global chunk k: (k + (m>>1)) & 3; (m>>1)&3 == ((lane&31)>>1)&3.
    const int m31 = lane & 31;
    const int h   = lane >> 5;
    const int clo = (2 * h + (m31 >> 1)) & 3;
    const int chi = (clo + 1) & 3;
    const int arow = wm * 64 + m31;       // + i*32
    const int brow = wn * 64 + m31;       // + j*32

    f32x16 acc[2][2];
    #pragma unroll
    for (int i = 0; i < 2; i++)
        #pragma unroll
        for (int j = 0; j < 2; j++)
            #pragma unroll
            for (int r = 0; r < 16; r++)
                acc[i][j][r] = 0.f;

    for (int k0 = 0; k0 < DIM; k0 += BKB) {
        __syncthreads();  // prior iter's LDS reads done
        #pragma unroll
        for (int s = 0; s < 2; s++) {
            const int sl = w * 32 + s * 16;   // slab start row; wave-uniform
            __builtin_amdgcn_global_load_lds(
                (const __attribute__((address_space(1))) void*)
                    (AgL + (size_t)s * 16 * DIM + k0),
                (__attribute__((address_space(3))) void*)(As + sl * BKB),
                16, 0, 0);
            __builtin_amdgcn_global_load_lds(
                (const __attribute__((address_space(1))) void*)
                    (BgL + (size_t)s * 16 * DIM + k0),
                (__attribute__((address_space(3))) void*)(Bs + sl * BKB),
                16, 0, 0);
        }
        __syncthreads();  // vmcnt drained by barrier semantics

        int8v af[2], bf[2];
        #pragma unroll
        for (int i = 0; i < 2; i++) {
            const unsigned char* pa = As + (arow + i * 32) * BKB;
            union { int8v v; struct { int4v lo, hi; } s; } ua;
            ua.s.lo = *(const int4v*)(pa + clo * 16);
            ua.s.hi = *(const int4v*)(pa + chi * 16);
            af[i] = ua.v;
            const unsigned char* pb = Bs + (brow + i * 32) * BKB;
            union { int8v v; struct { int4v lo, hi; } s; } ub;
            ub.s.lo = *(const int4v*)(pb + clo * 16);
            ub.s.hi = *(const int4v*)(pb + chi * 16);
            bf[i] = ub.v;
        }
        #pragma unroll
        for (int i = 0; i < 2; i++)
            #pragma unroll
            for (int j = 0; j < 2; j++)
                acc[i][j] = __builtin_amdgcn_mfma_scale_f32_32x32x64_f8f6f4(
                    af[i], bf[j], acc[i][j],
                    0, 0,               // cbsz=FP8(e4m3), blgp=FP8(e4m3)
                    0, 0x7F7F7F7F,      // opselA, scaleA = 1.0
                    0, 0x7F7F7F7F);     // opselB, scaleB = 1.0
    }

    // Epilogue: 32x32 C/D layout (m74/m101, dtype-independent):
    // col = lane&31, row = (r&3) + 8*(r>>2) + 4*(lane>>5).
    const int stripe = blockIdx.x * 2 + wn;
    #pragma unroll
    for (int i = 0; i < 2; i++) {
        #pragma unroll
        for (int r = 0; r < 16; r++) {
            float v = fmaxf(acc[i][0][r], acc[i][1][r]);
            v = fmaxf(v, __shfl_xor(v, 1));
            v = fmaxf(v, __shfl_xor(v, 2));
            v = fmaxf(v, __shfl_xor(v, 4));
            v = fmaxf(v, __shfl_xor(v, 8));
            v = fmaxf(v, __shfl_xor(v, 16));
            if (m31 == 0) {
                const int row = rowBase + wm * 64 + i * 32 +
                                (r & 3) + 8 * (r >> 2) + 4 * h;
                partial[(size_t)row * 128 + stripe] = v;   // = 256 * cos
            }
        }
    }
}

// ---------------- Kernel 3: stripe-max -> loss terms -> per-block partials --
__global__ __launch_bounds__(256) void reduce_kernel(
    const float* __restrict__ partial,
    const float* __restrict__ posdist,
    float* __restrict__ blockpart)   // [64][3]
{
    const int tid  = threadIdx.x;
    const int lane = tid & 63;
    const int w    = tid >> 6;
    __shared__ float red[4][3];

    float sloss = 0.f, spos = 0.f, shard = 0.f;

    #pragma unroll 4
    for (int i = 0; i < 32; i++) {
        const int row = blockIdx.x * 128 + w * 32 + i;
        float v = fmaxf(partial[(size_t)row * 128 + lane],
                        partial[(size_t)row * 128 + 64 + lane]);
        #pragma unroll
        for (int off = 1; off < 64; off <<= 1) v = fmaxf(v, __shfl_xor(v, off));
        if (lane == 0) {
            // v = 256*cos  ->  hard = (2 - 2*cos)/T = (2 - v/128)*TINV
            const float hard = (2.0f - 2.0f * v * INV_QSQ) * TINV;
            const float pos  = posdist[row];
            sloss += fmaxf(MARGIN + pos - hard, 0.0f);
            spos  += pos;
            shard += hard;
        }
    }
    if (lane == 0) { red[w][0] = sloss; red[w][1] = spos; red[w][2] = shard; }
    __syncthreads();
    if (tid == 0) {
        #pragma unroll
        for (int k = 0; k < 3; k++)
            blockpart[blockIdx.x * 3 + k] =
                red[0][k] + red[1][k] + red[2][k] + red[3][k];
    }
}

// ---------------- Kernel 4: finalize means (one wave, no atomics) -----------
__global__ __launch_bounds__(64) void finalize_kernel(
    const float* __restrict__ blockpart,
    float* __restrict__ out)
{
    const int lane = threadIdx.x;
    float a = blockpart[lane * 3 + 0];
    float b = blockpart[lane * 3 + 1];
    float c = blockpart[lane * 3 + 2];
    #pragma unroll
    for (int off = 1; off < 64; off <<= 1) {
        a += __shfl_xor(a, off);
        b += __shfl_xor(b, off);
        c += __shfl_xor(c, off);
    }
    if (lane == 0) {
        const float inv = 1.0f / (float)BS;
        out[0] = a * inv;
        out[1] = b * inv;
        out[2] = c * inv;
    }
}

extern "C" void kernel_launch(void* const* d_in, const int* in_sizes, int n_in,
                              void* d_out, int out_size, void* d_ws, size_t ws_size,
                              hipStream_t stream) {
    const float* feat = (const float*)d_in[0];
    char* ws = (char*)d_ws;

    // ws layout: Afp8 8MiB | Nfp8 8MiB | partial 4MiB | posdist 32KiB | blockpart
    unsigned char* Afp8      = (unsigned char*)ws;
    unsigned char* Nfp8      = (unsigned char*)(ws + ((size_t)8 << 20));
    float*         partial   = (float*)(ws + ((size_t)16 << 20));
    float*         posdist   = (float*)(ws + ((size_t)20 << 20));
    float*         blockpart = (float*)(ws + ((size_t)20 << 20) + 32768);

    normalize_kernel<<<BS, 256, 0, stream>>>(feat, Afp8, Nfp8, posdist);

    maxgemm_kernel<<<dim3(BS / BN, BS / BM), 256, 0, stream>>>(Afp8, Nfp8, partial);

    reduce_kernel<<<64, 256, 0, stream>>>(partial, posdist, blockpart);
    finalize_kernel<<<1, 64, 0, stream>>>(blockpart, (float*)d_out);
}

// Round 9
// 261.736 us; speedup vs baseline: 4.0623x; 1.4866x over previous
//
#include <hip/hip_runtime.h>

#define BS   8192
#define DIM  1024
#define TINV 10.0f    // 1 / TEMPERATURE
#define MARGIN 1.0f   // max(0.01, 1.0 - 0.1*0.0)

#define BM  128
#define BN  64
#define BKB 128       // fp8 K-bytes per staging iteration (16x16x128 MFMA)

// fp8 values are the normalized elements scaled by 16 -> dot = 256 * cos
#define QSCALE   16.0f
#define INV_QSQ  (1.0f / 256.0f)

typedef __attribute__((ext_vector_type(4))) float f32x4;
typedef __attribute__((ext_vector_type(4))) int   int4v;
typedef __attribute__((ext_vector_type(8))) int   int8v;

// ---------------- Kernel 1: L2-normalize rows, emit fp8(e4m3,x16) + posdist -
__global__ __launch_bounds__(256) void normalize_kernel(
    const float* __restrict__ feat,
    unsigned char* __restrict__ Afp8,
    unsigned char* __restrict__ Nfp8,
    float* __restrict__ posdist)
{
    const int row  = blockIdx.x;
    const int tid  = threadIdx.x;
    const int lane = tid & 63;
    const int w    = tid >> 6;
    __shared__ float red[4][4];

    const float4* fo = (const float4*)(feat + (size_t)row * DIM);
    const float4* fp = (const float4*)(feat + (size_t)(BS + row) * DIM);
    const float4* fn = (const float4*)(feat + (size_t)(2 * BS + row) * DIM);
    float4 o = fo[tid], p = fp[tid], n = fn[tid];

    float so = o.x*o.x + o.y*o.y + o.z*o.z + o.w*o.w;
    float sp = p.x*p.x + p.y*p.y + p.z*p.z + p.w*p.w;
    float sn = n.x*n.x + n.y*n.y + n.z*n.z + n.w*n.w;
    #pragma unroll
    for (int off = 1; off < 64; off <<= 1) {
        so += __shfl_xor(so, off);
        sp += __shfl_xor(sp, off);
        sn += __shfl_xor(sn, off);
    }
    if (lane == 0) { red[w][0] = so; red[w][1] = sp; red[w][2] = sn; }
    __syncthreads();
    so = red[0][0] + red[1][0] + red[2][0] + red[3][0];
    sp = red[0][1] + red[1][1] + red[2][1] + red[3][1];
    sn = red[0][2] + red[1][2] + red[2][2] + red[3][2];

    const float io  = 1.0f / fmaxf(sqrtf(so), 1e-12f);
    const float ip  = 1.0f / fmaxf(sqrtf(sp), 1e-12f);
    const float in_ = 1.0f / fmaxf(sqrtf(sn), 1e-12f);

    float ax = o.x*io, ay = o.y*io, az = o.z*io, aw = o.w*io;
    float px = p.x*ip, py = p.y*ip, pz = p.z*ip, pw = p.w*ip;
    float nx = n.x*in_, ny = n.y*in_, nz = n.z*in_, nw = n.w*in_;

    // e4m3 quantization with x16 pre-scale (avoids subnormals; max elem 16 << 448)
    int pa = __builtin_amdgcn_cvt_pk_fp8_f32(ax * QSCALE, ay * QSCALE, 0, false);
    pa     = __builtin_amdgcn_cvt_pk_fp8_f32(az * QSCALE, aw * QSCALE, pa, true);
    int pn = __builtin_amdgcn_cvt_pk_fp8_f32(nx * QSCALE, ny * QSCALE, 0, false);
    pn     = __builtin_amdgcn_cvt_pk_fp8_f32(nz * QSCALE, nw * QSCALE, pn, true);
    ((int*)(Afp8 + (size_t)row * DIM))[tid] = pa;
    ((int*)(Nfp8 + (size_t)row * DIM))[tid] = pn;

    float dx = ax - px, dy = ay - py, dz = az - pz, dw = aw - pw;
    float d = dx*dx + dy*dy + dz*dz + dw*dw;
    #pragma unroll
    for (int off = 1; off < 64; off <<= 1) d += __shfl_xor(d, off);
    if (lane == 0) red[w][3] = d;   // col 3: disjoint from cols 0..2 read above
    __syncthreads();
    if (tid == 0)
        posdist[row] = (red[0][3] + red[1][3] + red[2][3] + red[3][3]) * TINV;
}

// Load one 32B fragment from swizzled LDS: lo chunk at `off`, hi at off^16
// (chunk parity: (q2+1)^x == (q2^x)^1 for even q2). Union avoids repack.
__device__ __forceinline__ int8v ld_frag(const unsigned char* __restrict__ p,
                                         int off) {
    union { int8v v; struct { int4v lo, hi; } s; } u;
    u.s.lo = *(const int4v*)(p + off);
    u.s.hi = *(const int4v*)(p + (off ^ 16));
    return u.v;
}

// ---------------- Kernel 2: MX-fp8 16x16x128 MFMA max-GEMM ------------------
// R5 structure (best: 162 us) with HALVED per-wave footprint to raise
// occupancy NATURALLY (R6/R7: launch_bounds caps -> GB-scale spill; R8:
// 32x32 tile -> too little work per barrier, MfmaUtil 11.6%).
// Wave tile 32x64: acc 2x4xf32x4 = 32 VGPR, af[2]=16, bf[4]=32;
// essentials ~110 vs R5's ~175 -> expect 3-4 waves/SIMD at free allocation.
// Block tile 128x64; 8 independent MFMAs per wave-iter at K=128.
// LDS XOR-chunk swizzle (R4): LDS(row r, 16B chunk c) = global chunk c^(r&7).
__global__ __launch_bounds__(256) void maxgemm_kernel(
    const unsigned char* __restrict__ Afp8,
    const unsigned char* __restrict__ Nfp8,
    float* __restrict__ partial)   // [BS][128] row-major
{
    __shared__ unsigned char As[BM * BKB];
    __shared__ unsigned char Bs[BN * BKB];

    const int tid  = threadIdx.x;
    const int lane = tid & 63;
    const int w    = tid >> 6;
    const int rowBase = blockIdx.y * BM;
    const int colBase = blockIdx.x * BN;

    const int lrow = lane >> 3;                      // 0..7: row in 8-row slab
    const int gcol = ((lane & 7) ^ lrow) * 16;       // swizzled 16B chunk (bytes)

    const unsigned char* Ag = Afp8 + (size_t)rowBase * DIM;
    const unsigned char* Bg = Nfp8 + (size_t)colBase * DIM;

    // Per-lane LDS read offsets (XOR term row&7 is i/j-invariant: i*16 % 8 == 0)
    const int q2   = (lane >> 4) * 2;                // first 16B chunk of quad
    const int arow = w * 32 + (lane & 15);           // + i*16, i=0..1
    const int brow = (lane & 15);                    // + j*16, j=0..3
    const int aoff = arow * BKB + ((q2 ^ (arow & 7)) << 4);
    const int boff = brow * BKB + ((q2 ^ (brow & 7)) << 4);

    f32x4 acc[2][4];
    #pragma unroll
    for (int i = 0; i < 2; i++)
        #pragma unroll
        for (int j = 0; j < 4; j++)
            acc[i][j] = (f32x4){0.f, 0.f, 0.f, 0.f};

    for (int k0 = 0; k0 < DIM; k0 += BKB) {
        __syncthreads();  // prior iter's LDS reads done
        #pragma unroll
        for (int c = 0; c < 4; c++) {               // A: 4 slabs of 8 rows
            const int r0 = (w * 4 + c) * 8;
            __builtin_amdgcn_global_load_lds(
                (const __attribute__((address_space(1))) void*)
                    (Ag + (size_t)(r0 + lrow) * DIM + k0 + gcol),
                (__attribute__((address_space(3))) void*)(As + r0 * BKB),
                16, 0, 0);
        }
        #pragma unroll
        for (int s = 0; s < 2; s++) {               // B: 2 slabs of 8 rows
            const int r0 = (w * 2 + s) * 8;
            __builtin_amdgcn_global_load_lds(
                (const __attribute__((address_space(1))) void*)
                    (Bg + (size_t)(r0 + lrow) * DIM + k0 + gcol),
                (__attribute__((address_space(3))) void*)(Bs + r0 * BKB),
                16, 0, 0);
        }
        __syncthreads();  // vmcnt drained by barrier semantics

        int8v bf[4];
        #pragma unroll
        for (int j = 0; j < 4; j++)
            bf[j] = ld_frag(Bs, boff + j * 16 * BKB);

        #pragma unroll
        for (int i = 0; i < 2; i++) {
            const int8v a = ld_frag(As, aoff + i * 16 * BKB);
            #pragma unroll
            for (int j = 0; j < 4; j++)
                acc[i][j] = __builtin_amdgcn_mfma_scale_f32_16x16x128_f8f6f4(
                    a, bf[j], acc[i][j],
                    0, 0,               // cbsz=FP8(e4m3), blgp=FP8(e4m3)
                    0, 0x7F7F7F7F,      // opselA, scaleA = 1.0
                    0, 0x7F7F7F7F);     // opselB, scaleB = 1.0
        }
    }

    // Epilogue: per-row max over this block's 64 columns (all in this wave).
    // C/D layout (m89/m91): col = lane&15, row = (lane>>4)*4 + reg.
    const int stripe = blockIdx.x;
    #pragma unroll
    for (int i = 0; i < 2; i++) {
        #pragma unroll
        for (int r = 0; r < 4; r++) {
            float v = fmaxf(fmaxf(acc[i][0][r], acc[i][1][r]),
                            fmaxf(acc[i][2][r], acc[i][3][r]));
            v = fmaxf(v, __shfl_xor(v, 1));
            v = fmaxf(v, __shfl_xor(v, 2));
            v = fmaxf(v, __shfl_xor(v, 4));
            v = fmaxf(v, __shfl_xor(v, 8));
            if ((lane & 15) == 0) {
                const int row = rowBase + w * 32 + i * 16 + (lane >> 4) * 4 + r;
                partial[(size_t)row * 128 + stripe] = v;   // = 256 * cos
            }
        }
    }
}

// ---------------- Kernel 3: stripe-max -> loss terms -> per-block partials --
__global__ __launch_bounds__(256) void reduce_kernel(
    const float* __restrict__ partial,
    const float* __restrict__ posdist,
    float* __restrict__ blockpart)   // [64][3]
{
    const int tid  = threadIdx.x;
    const int lane = tid & 63;
    const int w    = tid >> 6;
    __shared__ float red[4][3];

    float sloss = 0.f, spos = 0.f, shard = 0.f;

    #pragma unroll 4
    for (int i = 0; i < 32; i++) {
        const int row = blockIdx.x * 128 + w * 32 + i;
        float v = fmaxf(partial[(size_t)row * 128 + lane],
                        partial[(size_t)row * 128 + 64 + lane]);
        #pragma unroll
        for (int off = 1; off < 64; off <<= 1) v = fmaxf(v, __shfl_xor(v, off));
        if (lane == 0) {
            // v = 256*cos  ->  hard = (2 - 2*cos)/T = (2 - v/128)*TINV
            const float hard = (2.0f - 2.0f * v * INV_QSQ) * TINV;
            const float pos  = posdist[row];
            sloss += fmaxf(MARGIN + pos - hard, 0.0f);
            spos  += pos;
            shard += hard;
        }
    }
    if (lane == 0) { red[w][0] = sloss; red[w][1] = spos; red[w][2] = shard; }
    __syncthreads();
    if (tid == 0) {
        #pragma unroll
        for (int k = 0; k < 3; k++)
            blockpart[blockIdx.x * 3 + k] =
                red[0][k] + red[1][k] + red[2][k] + red[3][k];
    }
}

// ---------------- Kernel 4: finalize means (one wave, no atomics) -----------
__global__ __launch_bounds__(64) void finalize_kernel(
    const float* __restrict__ blockpart,
    float* __restrict__ out)
{
    const int lane = threadIdx.x;
    float a = blockpart[lane * 3 + 0];
    float b = blockpart[lane * 3 + 1];
    float c = blockpart[lane * 3 + 2];
    #pragma unroll
    for (int off = 1; off < 64; off <<= 1) {
        a += __shfl_xor(a, off);
        b += __shfl_xor(b, off);
        c += __shfl_xor(c, off);
    }
    if (lane == 0) {
        const float inv = 1.0f / (float)BS;
        out[0] = a * inv;
        out[1] = b * inv;
        out[2] = c * inv;
    }
}

extern "C" void kernel_launch(void* const* d_in, const int* in_sizes, int n_in,
                              void* d_out, int out_size, void* d_ws, size_t ws_size,
                              hipStream_t stream) {
    const float* feat = (const float*)d_in[0];
    char* ws = (char*)d_ws;

    // ws layout: Afp8 8MiB | Nfp8 8MiB | partial 4MiB | posdist 32KiB | blockpart
    unsigned char* Afp8      = (unsigned char*)ws;
    unsigned char* Nfp8      = (unsigned char*)(ws + ((size_t)8 << 20));
    float*         partial   = (float*)(ws + ((size_t)16 << 20));
    float*         posdist   = (float*)(ws + ((size_t)20 << 20));
    float*         blockpart = (float*)(ws + ((size_t)20 << 20) + 32768);

    normalize_kernel<<<BS, 256, 0, stream>>>(feat, Afp8, Nfp8, posdist);

    maxgemm_kernel<<<dim3(BS / BN, BS / BM), 256, 0, stream>>>(Afp8, Nfp8, partial);

    reduce_kernel<<<64, 256, 0, stream>>>(partial, posdist, blockpart);
    finalize_kernel<<<1, 64, 0, stream>>>(blockpart, (float*)d_out);
}

// Round 10
// 258.111 us; speedup vs baseline: 4.1194x; 1.0140x over previous
//
#include <hip/hip_runtime.h>

#define BS   8192
#define DIM  1024
#define TINV 10.0f    // 1 / TEMPERATURE
#define MARGIN 1.0f   // max(0.01, 1.0 - 0.1*0.0)

#define BM  128
#define BN  64
#define BKB 128       // fp8 K-bytes per staging iteration (16x16x128 MFMA)

// fp8 values are the normalized elements scaled by 16 -> dot = 256 * cos
#define QSCALE   16.0f
#define INV_QSQ  (1.0f / 256.0f)

typedef __attribute__((ext_vector_type(4))) float f32x4;
typedef __attribute__((ext_vector_type(4))) int   int4v;
typedef __attribute__((ext_vector_type(8))) int   int8v;

// ---------------- Kernel 1: L2-normalize rows, emit fp8(e4m3,x16) + posdist -
// R10 rewrite: ONE WAVE PER ROW (was: one 256-thread block per row).
// R2-R9 residual (total - maxgemm) was a constant ~140-155 us; back-solving
// R2 puts normalize at ~100 us (~1 TB/s on a 112 MiB job) -- latency-bound:
// 1 float4/thread/stream in flight + 2 syncthreads + 2-phase LDS reduce.
// Now: 12 float4 in flight per lane, pure shfl_xor reduction, no LDS/syncs.
__global__ __launch_bounds__(256) void normalize_kernel(
    const float* __restrict__ feat,
    unsigned char* __restrict__ Afp8,
    unsigned char* __restrict__ Nfp8,
    float* __restrict__ posdist)
{
    const int lane = threadIdx.x & 63;
    const int row  = blockIdx.x * 4 + (threadIdx.x >> 6);   // wave = row

    const float4* fo = (const float4*)(feat + (size_t)row * DIM);
    const float4* fp = (const float4*)(feat + (size_t)(BS + row) * DIM);
    const float4* fn = (const float4*)(feat + (size_t)(2 * BS + row) * DIM);

    float4 o[4], p[4], n[4];
    #pragma unroll
    for (int k = 0; k < 4; k++) {
        o[k] = fo[lane + 64 * k];
        p[k] = fp[lane + 64 * k];
        n[k] = fn[lane + 64 * k];
    }

    float so = 0.f, sp = 0.f, sn = 0.f;
    #pragma unroll
    for (int k = 0; k < 4; k++) {
        so += o[k].x*o[k].x + o[k].y*o[k].y + o[k].z*o[k].z + o[k].w*o[k].w;
        sp += p[k].x*p[k].x + p[k].y*p[k].y + p[k].z*p[k].z + p[k].w*p[k].w;
        sn += n[k].x*n[k].x + n[k].y*n[k].y + n[k].z*n[k].z + n[k].w*n[k].w;
    }
    #pragma unroll
    for (int off = 1; off < 64; off <<= 1) {
        so += __shfl_xor(so, off);
        sp += __shfl_xor(sp, off);
        sn += __shfl_xor(sn, off);
    }

    const float io  = 1.0f / fmaxf(sqrtf(so), 1e-12f);
    const float ip  = 1.0f / fmaxf(sqrtf(sp), 1e-12f);
    const float in_ = 1.0f / fmaxf(sqrtf(sn), 1e-12f);

    int* Ar = (int*)(Afp8 + (size_t)row * DIM);
    int* Nr = (int*)(Nfp8 + (size_t)row * DIM);

    float d = 0.f;
    #pragma unroll
    for (int k = 0; k < 4; k++) {
        float ax = o[k].x*io, ay = o[k].y*io, az = o[k].z*io, aw = o[k].w*io;
        float nx = n[k].x*in_, ny = n[k].y*in_, nz = n[k].z*in_, nw = n[k].w*in_;
        int pa = __builtin_amdgcn_cvt_pk_fp8_f32(ax*QSCALE, ay*QSCALE, 0, false);
        pa     = __builtin_amdgcn_cvt_pk_fp8_f32(az*QSCALE, aw*QSCALE, pa, true);
        int pn = __builtin_amdgcn_cvt_pk_fp8_f32(nx*QSCALE, ny*QSCALE, 0, false);
        pn     = __builtin_amdgcn_cvt_pk_fp8_f32(nz*QSCALE, nw*QSCALE, pn, true);
        Ar[lane + 64 * k] = pa;      // coalesced 4B stores
        Nr[lane + 64 * k] = pn;
        float dx = ax - p[k].x*ip, dy = ay - p[k].y*ip;
        float dz = az - p[k].z*ip, dw = aw - p[k].w*ip;
        d += dx*dx + dy*dy + dz*dz + dw*dw;
    }
    #pragma unroll
    for (int off = 1; off < 64; off <<= 1) d += __shfl_xor(d, off);
    if (lane == 0) posdist[row] = d * TINV;
}

// Load one 32B fragment from swizzled LDS: lo chunk at `off`, hi at off^16
// (chunk parity: (q2+1)^x == (q2^x)^1 for even q2). Union avoids repack.
__device__ __forceinline__ int8v ld_frag(const unsigned char* __restrict__ p,
                                         int off) {
    union { int8v v; struct { int4v lo, hi; } s; } u;
    u.s.lo = *(const int4v*)(p + off);
    u.s.hi = *(const int4v*)(p + (off ^ 16));
    return u.v;
}

// ---------------- Kernel 2: MX-fp8 16x16x128 MFMA max-GEMM (R9, unchanged) --
// R9 measured: 107 us, VGPR 80, occupancy 30.5%, MfmaUtil 26.5%, no spill.
// Wave tile 32x64, block tile 128x64, LDS XOR-chunk swizzle.
__global__ __launch_bounds__(256) void maxgemm_kernel(
    const unsigned char* __restrict__ Afp8,
    const unsigned char* __restrict__ Nfp8,
    float* __restrict__ partial)   // [BS][128] row-major
{
    __shared__ unsigned char As[BM * BKB];
    __shared__ unsigned char Bs[BN * BKB];

    const int tid  = threadIdx.x;
    const int lane = tid & 63;
    const int w    = tid >> 6;
    const int rowBase = blockIdx.y * BM;
    const int colBase = blockIdx.x * BN;

    const int lrow = lane >> 3;                      // 0..7: row in 8-row slab
    const int gcol = ((lane & 7) ^ lrow) * 16;       // swizzled 16B chunk (bytes)

    const unsigned char* Ag = Afp8 + (size_t)rowBase * DIM;
    const unsigned char* Bg = Nfp8 + (size_t)colBase * DIM;

    const int q2   = (lane >> 4) * 2;                // first 16B chunk of quad
    const int arow = w * 32 + (lane & 15);           // + i*16, i=0..1
    const int brow = (lane & 15);                    // + j*16, j=0..3
    const int aoff = arow * BKB + ((q2 ^ (arow & 7)) << 4);
    const int boff = brow * BKB + ((q2 ^ (brow & 7)) << 4);

    f32x4 acc[2][4];
    #pragma unroll
    for (int i = 0; i < 2; i++)
        #pragma unroll
        for (int j = 0; j < 4; j++)
            acc[i][j] = (f32x4){0.f, 0.f, 0.f, 0.f};

    for (int k0 = 0; k0 < DIM; k0 += BKB) {
        __syncthreads();  // prior iter's LDS reads done
        #pragma unroll
        for (int c = 0; c < 4; c++) {               // A: 4 slabs of 8 rows
            const int r0 = (w * 4 + c) * 8;
            __builtin_amdgcn_global_load_lds(
                (const __attribute__((address_space(1))) void*)
                    (Ag + (size_t)(r0 + lrow) * DIM + k0 + gcol),
                (__attribute__((address_space(3))) void*)(As + r0 * BKB),
                16, 0, 0);
        }
        #pragma unroll
        for (int s = 0; s < 2; s++) {               // B: 2 slabs of 8 rows
            const int r0 = (w * 2 + s) * 8;
            __builtin_amdgcn_global_load_lds(
                (const __attribute__((address_space(1))) void*)
                    (Bg + (size_t)(r0 + lrow) * DIM + k0 + gcol),
                (__attribute__((address_space(3))) void*)(Bs + r0 * BKB),
                16, 0, 0);
        }
        __syncthreads();  // vmcnt drained by barrier semantics

        int8v bf[4];
        #pragma unroll
        for (int j = 0; j < 4; j++)
            bf[j] = ld_frag(Bs, boff + j * 16 * BKB);

        #pragma unroll
        for (int i = 0; i < 2; i++) {
            const int8v a = ld_frag(As, aoff + i * 16 * BKB);
            #pragma unroll
            for (int j = 0; j < 4; j++)
                acc[i][j] = __builtin_amdgcn_mfma_scale_f32_16x16x128_f8f6f4(
                    a, bf[j], acc[i][j],
                    0, 0,               // cbsz=FP8(e4m3), blgp=FP8(e4m3)
                    0, 0x7F7F7F7F,      // opselA, scaleA = 1.0
                    0, 0x7F7F7F7F);     // opselB, scaleB = 1.0
        }
    }

    // Epilogue: per-row max over this block's 64 columns (all in this wave).
    // C/D layout (m89/m91): col = lane&15, row = (lane>>4)*4 + reg.
    const int stripe = blockIdx.x;
    #pragma unroll
    for (int i = 0; i < 2; i++) {
        #pragma unroll
        for (int r = 0; r < 4; r++) {
            float v = fmaxf(fmaxf(acc[i][0][r], acc[i][1][r]),
                            fmaxf(acc[i][2][r], acc[i][3][r]));
            v = fmaxf(v, __shfl_xor(v, 1));
            v = fmaxf(v, __shfl_xor(v, 2));
            v = fmaxf(v, __shfl_xor(v, 4));
            v = fmaxf(v, __shfl_xor(v, 8));
            if ((lane & 15) == 0) {
                const int row = rowBase + w * 32 + i * 16 + (lane >> 4) * 4 + r;
                partial[(size_t)row * 128 + stripe] = v;   // = 256 * cos
            }
        }
    }
}

// ---------------- Kernel 3: stripe-max -> loss terms -> per-block partials --
__global__ __launch_bounds__(256) void reduce_kernel(
    const float* __restrict__ partial,
    const float* __restrict__ posdist,
    float* __restrict__ blockpart)   // [64][3]
{
    const int tid  = threadIdx.x;
    const int lane = tid & 63;
    const int w    = tid >> 6;
    __shared__ float red[4][3];

    float sloss = 0.f, spos = 0.f, shard = 0.f;

    #pragma unroll 4
    for (int i = 0; i < 32; i++) {
        const int row = blockIdx.x * 128 + w * 32 + i;
        float v = fmaxf(partial[(size_t)row * 128 + lane],
                        partial[(size_t)row * 128 + 64 + lane]);
        #pragma unroll
        for (int off = 1; off < 64; off <<= 1) v = fmaxf(v, __shfl_xor(v, off));
        if (lane == 0) {
            // v = 256*cos  ->  hard = (2 - 2*cos)/T = (2 - v/128)*TINV
            const float hard = (2.0f - 2.0f * v * INV_QSQ) * TINV;
            const float pos  = posdist[row];
            sloss += fmaxf(MARGIN + pos - hard, 0.0f);
            spos  += pos;
            shard += hard;
        }
    }
    if (lane == 0) { red[w][0] = sloss; red[w][1] = spos; red[w][2] = shard; }
    __syncthreads();
    if (tid == 0) {
        #pragma unroll
        for (int k = 0; k < 3; k++)
            blockpart[blockIdx.x * 3 + k] =
                red[0][k] + red[1][k] + red[2][k] + red[3][k];
    }
}

// ---------------- Kernel 4: finalize means (one wave, no atomics) -----------
__global__ __launch_bounds__(64) void finalize_kernel(
    const float* __restrict__ blockpart,
    float* __restrict__ out)
{
    const int lane = threadIdx.x;
    float a = blockpart[lane * 3 + 0];
    float b = blockpart[lane * 3 + 1];
    float c = blockpart[lane * 3 + 2];
    #pragma unroll
    for (int off = 1; off < 64; off <<= 1) {
        a += __shfl_xor(a, off);
        b += __shfl_xor(b, off);
        c += __shfl_xor(c, off);
    }
    if (lane == 0) {
        const float inv = 1.0f / (float)BS;
        out[0] = a * inv;
        out[1] = b * inv;
        out[2] = c * inv;
    }
}

extern "C" void kernel_launch(void* const* d_in, const int* in_sizes, int n_in,
                              void* d_out, int out_size, void* d_ws, size_t ws_size,
                              hipStream_t stream) {
    const float* feat = (const float*)d_in[0];
    char* ws = (char*)d_ws;

    // ws layout: Afp8 8MiB | Nfp8 8MiB | partial 4MiB | posdist 32KiB | blockpart
    unsigned char* Afp8      = (unsigned char*)ws;
    unsigned char* Nfp8      = (unsigned char*)(ws + ((size_t)8 << 20));
    float*         partial   = (float*)(ws + ((size_t)16 << 20));
    float*         posdist   = (float*)(ws + ((size_t)20 << 20));
    float*         blockpart = (float*)(ws + ((size_t)20 << 20) + 32768);

    normalize_kernel<<<BS / 4, 256, 0, stream>>>(feat, Afp8, Nfp8, posdist);

    maxgemm_kernel<<<dim3(BS / BN, BS / BM), 256, 0, stream>>>(Afp8, Nfp8, partial);

    reduce_kernel<<<64, 256, 0, stream>>>(partial, posdist, blockpart);
    finalize_kernel<<<1, 64, 0, stream>>>(blockpart, (float*)d_out);
}